// Round 1
// 426.764 us; speedup vs baseline: 1.0579x; 1.0579x over previous
//
#include <hip/hip_runtime.h>
#include <hip/hip_bf16.h>
#include <stdint.h>

#define VOCAB 32000
#define HID   256
#define BATCH 16
#define SEQT  256
#define ROWS  (BATCH*SEQT)   // 4096

typedef __attribute__((ext_vector_type(8))) short bf16x8_t;
typedef __attribute__((ext_vector_type(4))) float f32x4_t;

__device__ __forceinline__ short f2bs(float x) {
    __hip_bfloat16 h = __float2bfloat16(x);
    return *reinterpret_cast<short*>(&h);
}
__device__ __forceinline__ bf16x8_t cvt8(float4 a, float4 b) {
    union { short s[8]; bf16x8_t v; } u;
    u.s[0] = f2bs(a.x); u.s[1] = f2bs(a.y); u.s[2] = f2bs(a.z); u.s[3] = f2bs(a.w);
    u.s[4] = f2bs(b.x); u.s[5] = f2bs(b.y); u.s[6] = f2bs(b.z); u.s[7] = f2bs(b.w);
    return u.v;
}
// workgroup barrier draining ONLY lgkmcnt; vmem stays in flight
__device__ __forceinline__ void barrier_lds() {
    asm volatile("s_waitcnt lgkmcnt(0)\n\ts_barrier" ::: "memory");
}
// tanh via exp2: tanh(x) = 1 - 2/(2^(2*log2(e)*x)+1).
// 5 VALU ops/elem (mul, exp2, add, rcp, fma); saturates naturally at +-1
// (exp2->inf gives 1, exp2->0 gives -1); |err| ~1e-6, better than old CF5.
__device__ __forceinline__ float tanh_exp(float x) {
    float e = __builtin_amdgcn_exp2f(x * 2.885390081777927f);
    return fmaf(-2.f, __builtin_amdgcn_rcpf(e + 1.f), 1.f);
}
// pack two f32 -> one dword of 2 bf16 (RNE), lo = first operand
__device__ __forceinline__ uint32_t pk_bf16(float lo, float hi) {
    uint32_t r;
    asm("v_cvt_pk_bf16_f32 %0, %1, %2" : "=v"(r) : "v"(lo), "v"(hi));
    return r;
}

// ---------------------------------------------------------------------------
// K1: xp[t][b][h] = Wih[inputs[b][t]][h]+bih[h]+bhh[h]; also zeroes S and
// (optionally) converts Wfc fp32 -> bf16 into Wfcb. 4096 blocks x 256.
// ---------------------------------------------------------------------------
__global__ __launch_bounds__(256) void xproj_kernel(
    const int* __restrict__ inputs,
    const float* __restrict__ Wih,
    const float* __restrict__ bih,
    const float* __restrict__ bhh,
    const float* __restrict__ Wfc,
    float* __restrict__ xp,
    float* __restrict__ S,
    __hip_bfloat16* __restrict__ Wfcb,
    int do_cvt)
{
    int idx = blockIdx.x * 256 + threadIdx.x;  // (t*16+b)*256 + h
    int h  = idx & 255;
    int tb = idx >> 8;
    int b  = tb & 15;
    int t  = tb >> 4;
    int id = inputs[b * SEQT + t];
    xp[idx] = Wih[(size_t)id * HID + h] + bih[h] + bhh[h];
    if (idx < ROWS) S[idx] = 0.0f;
    if (do_cvt && idx < (VOCAB * HID / 8)) {
        const float4* p = (const float4*)(Wfc + (size_t)idx * 8);
        *(bf16x8_t*)((short*)Wfcb + (size_t)idx * 8) = cvt8(p[0], p[1]);
    }
}

// ---------------------------------------------------------------------------
// K2: RNN recurrence. One block, 512 threads (8 waves), M=16, N=K=256.
// VALU-issue-bound rewrite:
//  - n-tiles interleaved per lane (cols n0, n0+1) -> packed ds_write_b32
//    (conflict-free) + float2 x prefetch
//  - tanh via exp2 (5 ops/elem), v_cvt_pk_bf16_f32 pack
//  - x folded into MFMA C-in; t-loop unrolled 2x (static buffers, no moves)
// ---------------------------------------------------------------------------
__global__ __launch_bounds__(512, 1) void rnn_kernel(
    const float* __restrict__ xp,          // [T][B][H] fp32 (biases folded)
    const float* __restrict__ Whh,
    __hip_bfloat16* __restrict__ hs)       // [T][B][H] bf16
{
    __shared__ short hbuf[2][16][264];     // +8 pad
    const int tid = threadIdx.x;
    const int l = tid & 63, w = tid >> 6;
    const int lr = l & 15, lh = l >> 4;
    const int cm = tid >> 5;               // copy: row 0..15
    const int cc = (tid & 31) * 8;         // copy: col (x8 shorts)
    const int n0 = w * 32 + lr * 2;        // this lane's even column

    // B fragments: tile nt covers logical col n = n0+nt;
    // B[k][tilecol=lr] = Whh[n][k], k = ki*32 + lh*8 + j
    bf16x8_t bfrag[2][8];
#pragma unroll
    for (int nt = 0; nt < 2; nt++) {
#pragma unroll
        for (int ki = 0; ki < 8; ki++) {
            const float4* p = (const float4*)(Whh + (size_t)(n0 + nt) * HID + ki * 32 + lh * 8);
            bfrag[nt][ki] = cvt8(p[0], p[1]);
        }
    }
    for (int i = tid; i < 16 * 264; i += 512) ((short*)hbuf[0])[i] = 0;
    __syncthreads();

    // x prefetch, t=0: rows m=lh*4+r, cols (n0, n0+1) as one float2
    float2 xva[4], xvb[4];
#pragma unroll
    for (int r = 0; r < 4; r++)
        xva[r] = *(const float2*)(xp + (lh * 4 + r) * HID + n0);

    auto step = [&](int SRC, int DST, float2* xv, float2* xn, int t) {
        // pipelined copy of h_{t-1} (in hbuf[SRC]) to global hs
        if (t > 0) {
            bf16x8_t hv = *(const bf16x8_t*)(&hbuf[SRC][cm][cc]);
            *(bf16x8_t*)((short*)hs + (size_t)(t - 1) * (BATCH * HID) + cm * HID + cc) = hv;
        }
        // A fragments: A[m=lr][k=ki*32+lh*8+j]
        bf16x8_t afr[8];
#pragma unroll
        for (int ki = 0; ki < 8; ki++)
            afr[ki] = *(const bf16x8_t*)(&hbuf[SRC][lr][ki * 32 + lh * 8]);

        // two 4-deep chains per n-tile; x preloaded as C-in of chain a
        f32x4_t a0a = {xv[0].x, xv[1].x, xv[2].x, xv[3].x};
        f32x4_t a1a = {xv[0].y, xv[1].y, xv[2].y, xv[3].y};
        f32x4_t a0b = {0.f, 0.f, 0.f, 0.f};
        f32x4_t a1b = {0.f, 0.f, 0.f, 0.f};
#pragma unroll
        for (int ki = 0; ki < 4; ki++) {
            a0a = __builtin_amdgcn_mfma_f32_16x16x32_bf16(afr[ki],     bfrag[0][ki],     a0a, 0, 0, 0);
            a0b = __builtin_amdgcn_mfma_f32_16x16x32_bf16(afr[ki + 4], bfrag[0][ki + 4], a0b, 0, 0, 0);
            a1a = __builtin_amdgcn_mfma_f32_16x16x32_bf16(afr[ki],     bfrag[1][ki],     a1a, 0, 0, 0);
            a1b = __builtin_amdgcn_mfma_f32_16x16x32_bf16(afr[ki + 4], bfrag[1][ki + 4], a1b, 0, 0, 0);
        }

        // prefetch x_{t+1}; latency hidden behind MFMA + epilogue
        if (t + 1 < SEQT) {
            const float* xb = xp + (size_t)(t + 1) * (BATCH * HID);
#pragma unroll
            for (int r = 0; r < 4; r++)
                xn[r] = *(const float2*)(xb + (lh * 4 + r) * HID + n0);
        }

        // C/D: tilecol = lane&15 -> logical col n0+nt, row = (lane>>4)*4 + reg
#pragma unroll
        for (int r = 0; r < 4; r++) {
            float v0 = a0a[r] + a0b[r];
            float v1 = a1a[r] + a1b[r];
            uint32_t pk = pk_bf16(tanh_exp(v0), tanh_exp(v1));
            *(uint32_t*)(&hbuf[DST][lh * 4 + r][n0]) = pk;
        }
        barrier_lds();
    };

    for (int t = 0; t < SEQT; t += 2) {
        step(0, 1, xva, xvb, t);
        step(1, 0, xvb, xva, t + 1);
    }
    // final copy: h_{T-1} (written to buf 0 by step t=255)
    bf16x8_t hv = *(const bf16x8_t*)(&hbuf[0][cm][cc]);
    *(bf16x8_t*)((short*)hs + (size_t)(SEQT - 1) * (BATCH * HID) + cm * HID + cc) = hv;
}

// ---------------------------------------------------------------------------
// K3: fused FC GEMM + exp-rowsum + target-logit extraction.
// Tile 128m x 128n, K=256 in 8 slabs of 32. Double-buffered LDS, ONE
// lgkm-only barrier per slab, 2-slab register prefetch. XCD-swizzled grid:
// all 32 m-blocks of an n-panel land on one XCD -> B tile hits its L2.
// BF16B: B pre-converted to bf16 (else fp32 + inline cvt).
// ---------------------------------------------------------------------------
template <bool BF16B>
__global__ __launch_bounds__(256) void fc_kernel(
    const __hip_bfloat16* __restrict__ hs,
    const void* __restrict__ WfcP,
    const float* __restrict__ bfc,
    const int* __restrict__ targets,
    float* __restrict__ S,
    float* __restrict__ TL)
{
    __shared__ short As[2][4 * 128 * 8];
    __shared__ short Bs[2][4 * 128 * 8];
    __shared__ int tgt[128];

    const int bid = blockIdx.x;
    const int xcd = bid & 7;
    const int j   = bid >> 3;
    const int m_id = j & 31;
    const int n_id = (j >> 5) * 8 + xcd;
    if (n_id >= VOCAB / 128) return;
    const int m0 = m_id * 128, n0 = n_id * 128;

    const int tid = threadIdx.x;
    const int l = tid & 63, w = tid >> 6;
    const int lr = l & 15, lh = l >> 4;
    const int wm = (w >> 1) * 64, wn = (w & 1) * 64;
    const int row = tid & 127, sub = tid >> 7;   // 2 slots: (sub,row),(sub+2,row)

    if (tid < 128) {
        int r = m0 + tid;                        // r = t*16+b
        tgt[tid] = targets[((r & 15) << 8) | (r >> 4)];
    }

    f32x4_t acc[4][4];
    const f32x4_t z = {0.f, 0.f, 0.f, 0.f};
#pragma unroll
    for (int i = 0; i < 4; i++)
#pragma unroll
        for (int jj = 0; jj < 4; jj++) acc[i][jj] = z;

    const __hip_bfloat16* gA = hs + (size_t)(m0 + row) * HID + sub * 8;
    const __hip_bfloat16* gBb = (const __hip_bfloat16*)WfcP + (size_t)(n0 + row) * HID + sub * 8;
    const float*          gBf = (const float*)WfcP + (size_t)(n0 + row) * HID + sub * 8;

    bf16x8_t rA0, rA1, rB0, rB1;
    float4 rf0a, rf0b, rf1a, rf1b;

    // slab 0 -> LDS[0]
    {
        rA0 = *(const bf16x8_t*)(gA);
        rA1 = *(const bf16x8_t*)(gA + 16);
        *(bf16x8_t*)&As[0][(sub * 128 + row) * 8] = rA0;
        *(bf16x8_t*)&As[0][((sub + 2) * 128 + row) * 8] = rA1;
        if (BF16B) {
            rB0 = *(const bf16x8_t*)(gBb);
            rB1 = *(const bf16x8_t*)(gBb + 16);
            *(bf16x8_t*)&Bs[0][(sub * 128 + row) * 8] = rB0;
            *(bf16x8_t*)&Bs[0][((sub + 2) * 128 + row) * 8] = rB1;
        } else {
            const float4* p0 = (const float4*)(gBf);
            const float4* p1 = (const float4*)(gBf + 16);
            *(bf16x8_t*)&Bs[0][(sub * 128 + row) * 8] = cvt8(p0[0], p0[1]);
            *(bf16x8_t*)&Bs[0][((sub + 2) * 128 + row) * 8] = cvt8(p1[0], p1[1]);
        }
    }
    // prefetch slab 1
    {
        rA0 = *(const bf16x8_t*)(gA + 32);
        rA1 = *(const bf16x8_t*)(gA + 48);
        if (BF16B) {
            rB0 = *(const bf16x8_t*)(gBb + 32);
            rB1 = *(const bf16x8_t*)(gBb + 48);
        } else {
            rf0a = ((const float4*)(gBf + 32))[0]; rf0b = ((const float4*)(gBf + 32))[1];
            rf1a = ((const float4*)(gBf + 48))[0]; rf1b = ((const float4*)(gBf + 48))[1];
        }
    }
    __syncthreads();

    for (int s = 0; s < 8; s++) {
        const int buf = s & 1;
        bf16x8_t a[4], b[4];
#pragma unroll
        for (int mt = 0; mt < 4; mt++)
            a[mt] = *(const bf16x8_t*)&As[buf][(lh * 128 + wm + mt * 16 + lr) * 8];
#pragma unroll
        for (int nt = 0; nt < 4; nt++)
            b[nt] = *(const bf16x8_t*)&Bs[buf][(lh * 128 + wn + nt * 16 + lr) * 8];

        if (s + 1 < 8) {   // stage prefetched regs into the other buffer
            *(bf16x8_t*)&As[buf ^ 1][(sub * 128 + row) * 8] = rA0;
            *(bf16x8_t*)&As[buf ^ 1][((sub + 2) * 128 + row) * 8] = rA1;
            if (BF16B) {
                *(bf16x8_t*)&Bs[buf ^ 1][(sub * 128 + row) * 8] = rB0;
                *(bf16x8_t*)&Bs[buf ^ 1][((sub + 2) * 128 + row) * 8] = rB1;
            } else {
                *(bf16x8_t*)&Bs[buf ^ 1][(sub * 128 + row) * 8] = cvt8(rf0a, rf0b);
                *(bf16x8_t*)&Bs[buf ^ 1][((sub + 2) * 128 + row) * 8] = cvt8(rf1a, rf1b);
            }
        }
        if (s + 2 < 8) {   // 2-slab-deep global prefetch
            int k0 = (s + 2) * 32;
            rA0 = *(const bf16x8_t*)(gA + k0);
            rA1 = *(const bf16x8_t*)(gA + k0 + 16);
            if (BF16B) {
                rB0 = *(const bf16x8_t*)(gBb + k0);
                rB1 = *(const bf16x8_t*)(gBb + k0 + 16);
            } else {
                rf0a = ((const float4*)(gBf + k0))[0];      rf0b = ((const float4*)(gBf + k0))[1];
                rf1a = ((const float4*)(gBf + k0 + 16))[0]; rf1b = ((const float4*)(gBf + k0 + 16))[1];
            }
        }
#pragma unroll
        for (int mt = 0; mt < 4; mt++)
#pragma unroll
            for (int nt = 0; nt < 4; nt++)
                acc[mt][nt] = __builtin_amdgcn_mfma_f32_16x16x32_bf16(a[mt], b[nt], acc[mt][nt], 0, 0, 0);
        barrier_lds();
    }

    // epilogue: bias + exp + rowsum; extract target logits inline
    int tg[16];
#pragma unroll
    for (int i = 0; i < 16; i++)
        tg[i] = tgt[wm + (i >> 2) * 16 + lh * 4 + (i & 3)];

    float rsum[16];
#pragma unroll
    for (int i = 0; i < 16; i++) rsum[i] = 0.f;
#pragma unroll
    for (int nt = 0; nt < 4; nt++) {
        int n = n0 + wn + nt * 16 + lr;
        float bias = bfc[n];
#pragma unroll
        for (int mt = 0; mt < 4; mt++)
#pragma unroll
            for (int r = 0; r < 4; r++) {
                float v = acc[mt][nt][r] + bias;
                rsum[mt * 4 + r] += __expf(v);
                if (tg[mt * 4 + r] == n)
                    TL[m0 + wm + mt * 16 + lh * 4 + r] = v;
            }
    }
#pragma unroll
    for (int m = 1; m < 16; m <<= 1)
#pragma unroll
        for (int i = 0; i < 16; i++) rsum[i] += __shfl_xor(rsum[i], m, 64);
    if (lr == 0) {
#pragma unroll
        for (int i = 0; i < 16; i++) {
            int r = m0 + wm + (i >> 2) * 16 + lh * 4 + (i & 3);
            atomicAdd(&S[r], rsum[i]);
        }
    }
}

// ---------------------------------------------------------------------------
// K4: loss = mean_r( log(S[r]) - TL[r] )
// ---------------------------------------------------------------------------
__global__ __launch_bounds__(256) void loss_kernel(
    const float* __restrict__ S,
    const float* __restrict__ TL,
    float* __restrict__ out)
{
    int tid = threadIdx.x;
    float p = 0.f;
    for (int i = tid; i < ROWS; i += 256) p += __logf(S[i]) - TL[i];
#pragma unroll
    for (int m = 1; m < 64; m <<= 1) p += __shfl_xor(p, m, 64);
    __shared__ float red[4];
    if ((tid & 63) == 0) red[tid >> 6] = p;
    __syncthreads();
    if (tid == 0)
        out[0] = (red[0] + red[1] + red[2] + red[3]) / (float)ROWS;
}

extern "C" void kernel_launch(void* const* d_in, const int* in_sizes, int n_in,
                              void* d_out, int out_size, void* d_ws, size_t ws_size,
                              hipStream_t stream)
{
    (void)in_sizes; (void)n_in; (void)out_size;
    const int*   inputs  = (const int*)d_in[0];
    const int*   targets = (const int*)d_in[1];
    const float* Wih = (const float*)d_in[2];
    const float* bih = (const float*)d_in[3];
    const float* Whh = (const float*)d_in[4];
    const float* bhh = (const float*)d_in[5];
    const float* Wfc = (const float*)d_in[6];
    const float* bfc = (const float*)d_in[7];

    float* S  = (float*)d_ws;                           // 4096 f32
    float* TL = S + ROWS;                               // 4096 f32
    float* xp = TL + ROWS;                              // [T][B][H] fp32, 4 MB
    __hip_bfloat16* hs = (__hip_bfloat16*)(xp + (size_t)SEQT * BATCH * HID); // 2 MB
    __hip_bfloat16* Wfcb = hs + (size_t)ROWS * HID;     // 32000x256 bf16, 16 MB

    const size_t need = (size_t)(2 * ROWS) * 4 + (size_t)ROWS * HID * 4
                      + (size_t)ROWS * HID * 2 + (size_t)VOCAB * HID * 2;
    const int use_bf16b = (ws_size >= need) ? 1 : 0;

    xproj_kernel<<<(SEQT * BATCH * HID) / 256, 256, 0, stream>>>(
        inputs, Wih, bih, bhh, Wfc, xp, S, Wfcb, use_bf16b);
    rnn_kernel<<<1, 512, 0, stream>>>(xp, Whh, hs);
    if (use_bf16b)
        fc_kernel<true><<<8192, 256, 0, stream>>>(hs, (const void*)Wfcb, bfc, targets, S, TL);
    else
        fc_kernel<false><<<8192, 256, 0, stream>>>(hs, (const void*)Wfc, bfc, targets, S, TL);
    loss_kernel<<<1, 256, 0, stream>>>(S, TL, (float*)d_out);
}